// Round 8
// baseline (815.961 us; speedup 1.0000x reference)
//
#include <hip/hip_runtime.h>
#include <hip/hip_fp16.h>

#define KAPPA 0.99f
#define T_MAX 32

typedef unsigned short u16;
typedef _Float16 f16x8 __attribute__((ext_vector_type(8)));
typedef float f32x4 __attribute__((ext_vector_type(4)));

static __device__ __forceinline__ f16x8 bc16(uint4 u) {
  union { uint4 a; f16x8 b; } x;
  x.a = u;
  return x.b;
}

// ---------- Projection of each row of W onto the L1 ball of radius KAPPA ----------
__global__ __launch_bounds__(64) void proj_kernel(const float* __restrict__ W,
                                                  u16* __restrict__ Wp16) {
  __shared__ float a[128];
  __shared__ float css[128];
  __shared__ float s_alpha, s_l1;
  int row = blockIdx.x;
  int t = threadIdx.x;
  a[t]      = fabsf(W[row * 128 + t]);
  a[t + 64] = fabsf(W[row * 128 + t + 64]);
  __syncthreads();
  for (int k = 2; k <= 128; k <<= 1) {
    for (int j = k >> 1; j > 0; j >>= 1) {
      int i = 2 * t - (t & (j - 1));
      int ixj = i ^ j;
      bool up = ((i & k) == 0);
      float x = a[i], y = a[ixj];
      if ((x > y) == up) { a[i] = y; a[ixj] = x; }
      __syncthreads();
    }
  }
  if (t == 0) {
    float csum = 0.f;
    int cnt = 0;
    for (int j = 0; j < 128; ++j) {
      float ad = a[127 - j];
      csum += ad;
      float c = csum - KAPPA;
      css[j] = c;
      if (ad * (float)(j + 1) > c) cnt++;
    }
    s_alpha = css[cnt - 1] / (float)cnt;
    s_l1 = csum;
  }
  __syncthreads();
  float alpha = s_alpha;
  bool doproj = (s_l1 > KAPPA);
  for (int idx = t; idx < 128; idx += 64) {
    float w = W[row * 128 + idx];
    float pp = fmaxf(fabsf(w) - alpha, 0.f);
    float res = doproj ? ((w >= 0.f) ? pp : -pp) : w;
    Wp16[row * 128 + idx] = __half_as_ushort(__float2half_rn(res));
  }
}

// repack Wp16 into MFMA A-fragment order (frag = mt*4+kt)
__global__ __launch_bounds__(256) void wpa_kernel(const u16* __restrict__ Wp16,
                                                  u16* __restrict__ WpA) {
  int idx = blockIdx.x * 256 + threadIdx.x;  // < 2048
  int l = idx & 63, frag = idx >> 6;
  int mt = frag >> 2, kt = frag & 3;
  int m = mt * 16 + (l & 15);
  int k0 = kt * 32 + (l >> 4) * 8;
  u16* dst = WpA + (size_t)idx * 8;
#pragma unroll
  for (int i = 0; i < 8; ++i) dst[i] = Wp16[m * 128 + k0 + i];
}

// ---------- 128x128 transpose (Omega -> OmegaT, fp32) ----------
__global__ __launch_bounds__(256) void transpose128(const float* __restrict__ A,
                                                    float* __restrict__ AT) {
  int idx = blockIdx.x * 256 + threadIdx.x;
  int f = idx >> 7, p = idx & 127;
  AT[p * 128 + f] = A[idx];
}

// ---------- CSR build ----------
__global__ __launch_bounds__(256) void hist_kernel(const int* __restrict__ col,
                                                   int* __restrict__ counts, int E) {
  int e = blockIdx.x * 256 + threadIdx.x;
  if (e < E) atomicAdd(&counts[col[e]], 1);
}

__global__ __launch_bounds__(256) void scanA(const int* __restrict__ counts,
                                             int* __restrict__ offs,
                                             int* __restrict__ bsums, int N) {
  __shared__ int tmp[256];
  int t = threadIdx.x, i = blockIdx.x * 256 + t;
  int v = (i < N) ? counts[i] : 0;
  tmp[t] = v;
  __syncthreads();
  for (int d = 1; d < 256; d <<= 1) {
    int u = (t >= d) ? tmp[t - d] : 0;
    __syncthreads();
    tmp[t] += u;
    __syncthreads();
  }
  if (i < N) offs[i] = tmp[t] - v;
  if (t == 255) bsums[blockIdx.x] = tmp[255];
}

__global__ __launch_bounds__(256) void scanB(int* __restrict__ bsums, int nb) {
  __shared__ int tmp[256];
  int t = threadIdx.x;
  int v = (t < nb) ? bsums[t] : 0;
  tmp[t] = v;
  __syncthreads();
  for (int d = 1; d < 256; d <<= 1) {
    int u = (t >= d) ? tmp[t - d] : 0;
    __syncthreads();
    tmp[t] += u;
    __syncthreads();
  }
  if (t < nb) bsums[t] = tmp[t] - v;
}

__global__ __launch_bounds__(256) void scanC(int* __restrict__ offs,
                                             const int* __restrict__ bsums,
                                             int* __restrict__ cursors, int N, int E) {
  int i = blockIdx.x * 256 + threadIdx.x;
  if (i < N) {
    int o = offs[i] + bsums[blockIdx.x];
    offs[i] = o;
    cursors[i] = o;
  }
  if (i == 0) offs[N] = E;
}

// packed (row, val) per edge
__global__ __launch_bounds__(256) void scatter_kernel(const int* __restrict__ erow,
                                                      const int* __restrict__ ecol,
                                                      const float* __restrict__ eval,
                                                      int* __restrict__ cursors,
                                                      int2* __restrict__ cpair, int E) {
  int e = blockIdx.x * 256 + threadIdx.x;
  if (e < E) {
    int c = ecol[e];
    int pos = atomicAdd(&cursors[c], 1);
    cpair[pos] = make_int2(erow[e], __float_as_int(eval[e]));
  }
}

// ================= two-level grid barrier, v3 =================
// Designed around the two measured failure modes:
//  - R5 livelock: a RELAXED release STORE can sit dirty in the writer XCD's L2
//    forever (per-XCD L2s non-coherent). Fix: release via atomic RMW
//    (fetch_max, RELEASE) -- RMWs serialize at the coherent point.
//  - R3 slowness: ACQ_REL/ACQUIRE on every arrival & poll = per-op cache
//    maintenance x1024. Fix: arrivals are RELAXED RMWs (two-level, 8 parallel
//    group lines); polls are RELAXED loads with an ACQUIRE rescue poll every
//    16th iteration (guarantees progress if relaxed loads serve stale lines,
//    at 1/16th of the acquire cost). s_sleep(1) tightens detect latency vs
//    cg.sync's coarse backoff.
// Data fences: ONE __threadfence release before arrival, ONE after observing
// (same pair cg::grid.sync uses). Replay-safe relative-base targets (R3-proven
// scheme). Bounded spin as emergency valve.
__device__ __forceinline__ void gbar3(unsigned* __restrict__ bc, int nb,
                                      unsigned target, int tid, int bid) {
  __syncthreads();
  if (tid == 0) {
    __threadfence();  // release this block's data writes
    int g = bid & 7;
    unsigned m = (unsigned)(nb >> 3);  // nb is a multiple of 8
    unsigned a = __hip_atomic_fetch_add(&bc[g * 16], 1u, __ATOMIC_RELAXED,
                                        __HIP_MEMORY_SCOPE_AGENT);
    if (a == target * m - 1u) {  // last arriver of this group for this phase
      unsigned b = __hip_atomic_fetch_add(&bc[128], 1u, __ATOMIC_RELAXED,
                                          __HIP_MEMORY_SCOPE_AGENT);
      if (b == target * 8u - 1u)
        (void)__hip_atomic_fetch_max(&bc[144], target, __ATOMIC_RELEASE,
                                     __HIP_MEMORY_SCOPE_AGENT);  // RMW: coherent
    }
    unsigned spins = 0;
    for (;;) {
      unsigned v;
      if ((spins & 15u) == 15u)
        v = __hip_atomic_load(&bc[144], __ATOMIC_ACQUIRE,
                              __HIP_MEMORY_SCOPE_AGENT);  // rescue: always fresh
      else
        v = __hip_atomic_load(&bc[144], __ATOMIC_RELAXED,
                              __HIP_MEMORY_SCOPE_AGENT);
      if (v >= target) break;
      __builtin_amdgcn_s_sleep(1);
      if (++spins > 2000000u) break;  // emergency valve: fail, don't hang
    }
  }
  __syncthreads();
  __threadfence();  // acquire side: discard stale lines before reading data
}

// ================= device helpers =================

__device__ __forceinline__ void store_half16(u16* dst, const float* acc) {
  union { u16 us[16]; uint4 q[2]; } pk;
#pragma unroll
  for (int k = 0; k < 16; ++k) pk.us[k] = __half_as_ushort(__float2half_rn(acc[k]));
  uint4* d4 = (uint4*)dst;
  d4[0] = pk.q[0];
  d4[1] = pk.q[1];
}

// Phase A: Yh = fp16(Omega @ U), feature-major U read
__device__ __forceinline__ void u_gemm_phase(const float* __restrict__ U,
                                             const float* __restrict__ OmT,
                                             u16* __restrict__ Yh, int N, int ntiles,
                                             int bid, int nblocks, int tid) {
  int n = tid & 63;
  int fg = __builtin_amdgcn_readfirstlane(tid >> 6);
  for (int tile = bid; tile < ntiles; tile += nblocks) {
    int node = tile * 64 + n;
    int nc = min(node, N - 1);
    float acc[16];
#pragma unroll
    for (int k = 0; k < 16; ++k) acc[k] = 0.f;
    for (int j = 0; j < 128; ++j) {
      float x = U[(size_t)j * N + nc];
      const float* wr = OmT + j * 128 + fg * 16;
#pragma unroll
      for (int k = 0; k < 16; ++k) acc[k] = fmaf(wr[k], x, acc[k]);
    }
    if (node < N) store_half16(Yh + (size_t)node * 128 + fg * 16, acc);
  }
}

// 8-way-split error slots: max over groups
__device__ __forceinline__ float err_at(const unsigned* __restrict__ errs, int t) {
  unsigned m = 0u;
#pragma unroll
  for (int g = 0; g < 8; ++g) {
    unsigned v = __hip_atomic_load(errs + t * 8 + g, __ATOMIC_RELAXED,
                                   __HIP_MEMORY_SCOPE_AGENT);
    m = (v > m) ? v : m;
  }
  return __uint_as_float(m);
}

// stop rule, robust to the fp16 quantization floor
__device__ __forceinline__ bool stop_rule(float e, float prev) {
  return (e < 2e-3f) || (e < 4e-3f && e < 0.6f * prev) ||
         (e < 3e-3f && e > 0.9f * prev);
}

__device__ __forceinline__ void load_afrags(const u16* __restrict__ WpA, int wave,
                                            int lane, f16x8* afrag) {
  const uint4* ag = (const uint4*)WpA;
#pragma unroll
  for (int kt = 0; kt < 4; ++kt) afrag[kt] = bc16(ag[(wave * 4 + kt) * 64 + lane]);
}

// Fused pass over statically partitioned 32-node tiles. Double-buffered
// synchronous Jacobi (R1's proven-fastest structure).
// Lockstep gather: the wave's 4 rows advance together in 8-deep chunks
// (32 Y-gathers in flight). Rows clamped to N-1: duplicate writes benign.
// mode 0 (seed): B=gather(Y); Bh=Xh=fp16(B); Ydst=fp16(Wp@B)
// mode 1 (step): x=relu(gather(Y)+B); err vs Xh; Xh=fp16(x); Ydst=fp16(Wp@x)
__device__ __forceinline__ void fused_tile_pass(
    const u16* __restrict__ Ysrc, u16* __restrict__ Ydst,
    const int* __restrict__ offs, const int2* __restrict__ cpair,
    u16* __restrict__ Bh, u16* __restrict__ Xh, int N, int mode,
    unsigned* err_slot, const f16x8* afrag, __half2 (*xs)[72],
    float* werr, int bid, int nblocks, int tid, int lane, int wave) {
  const __half2* Y2 = (const __half2*)Ysrc;
  __half2* B2 = (__half2*)Bh;
  __half2* X2 = (__half2*)Xh;
  int ntiles = (N + 31) >> 5;
  float m = 0.f;
  for (int tile = bid; tile < ntiles; tile += nblocks) {
    __syncthreads();  // prev tile's MFMA reads of xs done
    int base = tile * 32;
    int cq[4], end[4], last[4], e[4];
    float ax[4], ay[4];
#pragma unroll
    for (int q = 0; q < 4; ++q) {
      int c = base + wave * 4 + q;
      cq[q] = min(c, N - 1);
      int b = offs[cq[q]];
      end[q] = offs[cq[q] + 1];
      last[q] = (end[q] > b) ? (end[q] - 1) : 0;
      e[q] = b;
      ax[q] = 0.f;
      ay[q] = 0.f;
    }
    for (;;) {
      int more = 0;
#pragma unroll
      for (int q = 0; q < 4; ++q) more |= (e[q] < end[q]) ? 1 : 0;
      if (!more) break;
      int addr[4][8];
      float val[4][8];
#pragma unroll
      for (int q = 0; q < 4; ++q) {
#pragma unroll
        for (int i = 0; i < 8; ++i) {
          int idx = e[q] + i;
          int cl = (idx <= last[q]) ? idx : last[q];
          int2 pp = cpair[cl];
          addr[q][i] = pp.x * 64 + lane;
          val[q][i] = (idx < end[q]) ? __int_as_float(pp.y) : 0.f;
        }
      }
      __half2 h[4][8];
#pragma unroll
      for (int q = 0; q < 4; ++q)
#pragma unroll
        for (int i = 0; i < 8; ++i) h[q][i] = Y2[addr[q][i]];
#pragma unroll
      for (int q = 0; q < 4; ++q)
#pragma unroll
        for (int i = 0; i < 8; ++i) {
          ax[q] = fmaf(val[q][i], __low2float(h[q][i]), ax[q]);
          ay[q] = fmaf(val[q][i], __high2float(h[q][i]), ay[q]);
        }
#pragma unroll
      for (int q = 0; q < 4; ++q) e[q] += 8;
    }
#pragma unroll
    for (int q = 0; q < 4; ++q) {
      int nl = wave * 4 + q;
      size_t wi = (size_t)cq[q] * 64 + lane;
      float axv = ax[q], ayv = ay[q];
      if (mode == 0) {
        __half2 hh = __floats2half2_rn(axv, ayv);
        B2[wi] = hh;
        X2[wi] = hh;
        xs[nl][lane] = hh;
      } else {
        __half2 b = B2[wi];
        axv = fmaxf(axv + __low2float(b), 0.f);
        ayv = fmaxf(ayv + __high2float(b), 0.f);
        __half2 xo = X2[wi];
        m = fmaxf(m, fmaxf(fabsf(axv - __low2float(xo)),
                           fabsf(ayv - __high2float(xo))));
        __half2 hh = __floats2half2_rn(axv, ayv);
        X2[wi] = hh;
        xs[nl][lane] = hh;
      }
    }
    __syncthreads();
    // MFMA: wave w computes M-tile w of Wp @ X(128x32)
    f32x4 acc0 = {0.f, 0.f, 0.f, 0.f};
    f32x4 acc1 = {0.f, 0.f, 0.f, 0.f};
    int nA = lane & 15;
    int q4 = (lane >> 4) * 4;
#pragma unroll
    for (int kt = 0; kt < 4; ++kt) {
      int h0 = kt * 16 + q4;
      f16x8 b0 = bc16(*(const uint4*)&xs[nA][h0]);
      f16x8 b1 = bc16(*(const uint4*)&xs[16 + nA][h0]);
      acc0 = __builtin_amdgcn_mfma_f32_16x16x32_f16(afrag[kt], b0, acc0, 0, 0, 0);
      acc1 = __builtin_amdgcn_mfma_f32_16x16x32_f16(afrag[kt], b1, acc1, 0, 0, 0);
    }
    // D layout: col=lane&15 (node), row=(lane>>4)*4+reg (feat in M-tile)
    int fb = wave * 16 + q4;
    int n0 = base + nA;
    if (n0 < N) {
      __half2* d = (__half2*)(Ydst + (size_t)n0 * 128 + fb);
      d[0] = __floats2half2_rn(acc0.x, acc0.y);
      d[1] = __floats2half2_rn(acc0.z, acc0.w);
    }
    int n1 = base + 16 + nA;
    if (n1 < N) {
      __half2* d = (__half2*)(Ydst + (size_t)n1 * 128 + fb);
      d[0] = __floats2half2_rn(acc1.x, acc1.y);
      d[1] = __floats2half2_rn(acc1.z, acc1.w);
    }
  }
  if (mode == 1) {
#pragma unroll
    for (int o = 32; o > 0; o >>= 1) m = fmaxf(m, __shfl_xor(m, o, 64));
    if (lane == 0) werr[wave] = m;
    __syncthreads();
    if (tid == 0) {
      float bm = werr[0];
#pragma unroll
      for (int w = 1; w < 8; ++w) bm = fmaxf(bm, werr[w]);
      atomicMax(err_slot + (bid & 7), __float_as_uint(bm));  // 8-way split
    }
  }
}

// Output pass: out[f][node] = float(Xh[node][f]), transposed via LDS.
// Tile partition matches fused_tile_pass: block reads only rows it wrote.
__device__ __forceinline__ void xh_transpose_pass(const u16* __restrict__ Xh,
                                                  float* __restrict__ out, int N,
                                                  float (*Ts)[129], int bid,
                                                  int nblocks, int tid) {
  const uint4* X4 = (const uint4*)Xh;  // 16 uint4 per 128-feat row
  int ntiles = (N + 31) >> 5;
  for (int tile = bid; tile < ntiles; tile += nblocks) {
    __syncthreads();
    int base = tile * 32;
    {
      int nn = tid >> 4, cc = tid & 15;  // 512 threads = 32 rows x 16 uint4
      uint4 q = make_uint4(0, 0, 0, 0);
      if (base + nn < N) q = X4[(size_t)(base + nn) * 16 + cc];
      f16x8 h = bc16(q);
      float* dst = &Ts[nn][cc * 8];
#pragma unroll
      for (int j = 0; j < 8; ++j) dst[j] = (float)h[j];
    }
    __syncthreads();
    int n = tid & 31, f0 = tid >> 5;
    int node = base + n;
    if (node < N) {
#pragma unroll
      for (int k = 0; k < 8; ++k) {
        int f = f0 + k * 16;
        out[(size_t)f * N + node] = Ts[n][f];
      }
    }
  }
}

// ================= cooperative solver (R1 structure, gbar3 barrier) ===========
__global__ __launch_bounds__(512, 4) void solve_kernel(
    const float* __restrict__ U, const float* __restrict__ OmT,
    const u16* __restrict__ WpA, const int* __restrict__ offs,
    const int2* __restrict__ cpair, u16* __restrict__ Ya, u16* __restrict__ Yb,
    u16* __restrict__ Bh, u16* __restrict__ Xh, float* __restrict__ out,
    unsigned* __restrict__ errs, unsigned* __restrict__ barc, int N) {
  __shared__ __align__(16) char lds_raw[32 * 129 * 4];  // Ts(16512) >= xs(9216)
  __shared__ float werr[8];
  __shared__ float s_e;
  __half2 (*xs)[72] = (__half2(*)[72])lds_raw;
  float (*Ts)[129] = (float(*)[129])lds_raw;
  const int tid = threadIdx.x;
  const int bid = blockIdx.x, nblocks = gridDim.x;
  const int lane = tid & 63, wave = tid >> 6;
  const int ntiles64 = (N + 63) >> 6;

  // replay-safe base (fresh read): barrier state is quiescent at entry; all
  // blocks see the same value since no release can precede full arrival.
  unsigned bbase = 0;
  if (tid == 0)
    bbase = __hip_atomic_load(&barc[144], __ATOMIC_ACQUIRE,
                              __HIP_MEMORY_SCOPE_AGENT);
  unsigned ph = 0;

  f16x8 afrag[4];
  load_afrags(WpA, wave, lane, afrag);

  u_gemm_phase(U, OmT, Ya, N, ntiles64, bid, nblocks, tid);
  ++ph;
  gbar3(barc, nblocks, bbase + ph, tid, bid);
  // seed: B = gather(Om@U from Ya); X0 = B; Yb = Wp@B
  fused_tile_pass(Ya, Yb, offs, cpair, Bh, Xh, N, 0, nullptr, afrag, xs, werr,
                  bid, nblocks, tid, lane, wave);
  ++ph;
  gbar3(barc, nblocks, bbase + ph, tid, bid);

  u16* cur = Yb;
  u16* nxt = Ya;
  float prev = 3.0e38f;
  for (int t = 1; t <= T_MAX; ++t) {
    fused_tile_pass(cur, nxt, offs, cpair, Bh, Xh, N, 1, errs + t * 8, afrag, xs,
                    werr, bid, nblocks, tid, lane, wave);
    ++ph;
    gbar3(barc, nblocks, bbase + ph, tid, bid);
    if (tid == 0) s_e = err_at(errs, t);
    __syncthreads();
    float e = s_e;
    u16* tmp = cur; cur = nxt; nxt = tmp;
    if (stop_rule(e, prev)) break;  // grid-uniform: same slots read by all blocks
    prev = e;
  }

  // output X_T directly (block reads only tiles it wrote: no barrier needed)
  xh_transpose_pass(Xh, out, N, Ts, bid, nblocks, tid);
}

// ================= fallback multi-kernel path (R4, known-good) =================
__global__ __launch_bounds__(512) void u_gemm_kernel(const float* __restrict__ U,
                                                     const float* __restrict__ OmT,
                                                     u16* __restrict__ Yh, int N) {
  u_gemm_phase(U, OmT, Yh, N, (N + 63) >> 6, blockIdx.x, gridDim.x, threadIdx.x);
}

__global__ __launch_bounds__(512, 4) void step_kernel(
    const u16* __restrict__ Ysrc, u16* __restrict__ Ydst,
    const u16* __restrict__ WpA, const int* __restrict__ offs,
    const int2* __restrict__ cpair, u16* __restrict__ Bh, u16* __restrict__ Xh,
    int N, unsigned* __restrict__ errs, int* __restrict__ flags, int t, int mode) {
  if (mode == 1 && t > 1) {
    int sf = __hip_atomic_load(&flags[64], __ATOMIC_RELAXED,
                               __HIP_MEMORY_SCOPE_AGENT);
    if (sf != 0 && t > sf) return;
  }
  __shared__ __align__(16) __half2 xs[32][72];
  __shared__ float werr[8];
  int lane = threadIdx.x & 63, wave = threadIdx.x >> 6;
  f16x8 afrag[4];
  load_afrags(WpA, wave, lane, afrag);
  // one tile per block: bid indexes the tile, nblocks = ntiles
  fused_tile_pass(Ysrc, Ydst, offs, cpair, Bh, Xh, N, mode,
                  (mode == 1) ? (errs + t * 8) : nullptr, afrag, xs, werr,
                  blockIdx.x, gridDim.x, threadIdx.x, lane, wave);
  if (mode == 1 && threadIdx.x == 0) {
    __threadfence();
    int old = __hip_atomic_fetch_add(&flags[t], 1, __ATOMIC_ACQ_REL,
                                     __HIP_MEMORY_SCOPE_AGENT);
    if (old == (int)gridDim.x - 1) {
      float e = err_at(errs, t);
      float prev = (t > 1) ? err_at(errs, t - 1) : 3.0e38f;
      int fired = stop_rule(e, prev) ? t : 0;
      if (t == 1)
        __hip_atomic_store(&flags[64], fired, __ATOMIC_RELEASE,
                           __HIP_MEMORY_SCOPE_AGENT);
      else if (fired && __hip_atomic_load(&flags[64], __ATOMIC_RELAXED,
                                          __HIP_MEMORY_SCOPE_AGENT) == 0)
        __hip_atomic_store(&flags[64], fired, __ATOMIC_RELEASE,
                           __HIP_MEMORY_SCOPE_AGENT);
    }
  }
}

__global__ __launch_bounds__(512) void final_kernel(const u16* __restrict__ Xh,
                                                    float* __restrict__ out, int N) {
  __shared__ float Ts[32][129];
  xh_transpose_pass(Xh, out, N, Ts, blockIdx.x, gridDim.x, threadIdx.x);
}

extern "C" void kernel_launch(void* const* d_in, const int* in_sizes, int n_in,
                              void* d_out, int out_size, void* d_ws, size_t ws_size,
                              hipStream_t stream) {
  const float* W     = (const float*)d_in[0];
  const float* Om    = (const float*)d_in[1];
  const float* U     = (const float*)d_in[2];
  const float* evalp = (const float*)d_in[3];
  const int*   erow  = (const int*)d_in[4];
  const int*   ecol  = (const int*)d_in[5];

  int N = in_sizes[2] / 128;
  int E = in_sizes[3];

  char* p = (char*)d_ws;
  auto alloc = [&](size_t bytes) {
    char* r = p;
    p += (bytes + 255) & ~(size_t)255;
    return r;
  };
  u16* Wp16      = (u16*)alloc(128 * 128 * 2);
  u16* WpA       = (u16*)alloc(32 * 64 * 8 * 2);  // MFMA A-fragment layout
  float* OmT     = (float*)alloc(128 * 128 * 4);
  int* counts    = (int*)alloc((size_t)(N + 1) * 4);
  int* offs      = (int*)alloc((size_t)(N + 1) * 4);
  int* cursors   = (int*)alloc((size_t)N * 4);
  int* bsums     = (int*)alloc(1024 * 4);
  unsigned* errs = (unsigned*)alloc(512 * 4);   // [t*8+group] split err slots
  unsigned* barc = (unsigned*)alloc(256 * 4);   // two-level barrier state
  int* flags     = (int*)alloc(256 * 4);        // fallback arrive/stop state
  int2* cpair    = (int2*)alloc((size_t)E * 8); // packed (row, val_bits)
  u16* Ya        = (u16*)alloc((size_t)N * 128 * 2);
  u16* Yb        = (u16*)alloc((size_t)N * 128 * 2);
  u16* Bh        = (u16*)alloc((size_t)N * 128 * 2);
  u16* Xh        = (u16*)alloc((size_t)N * 128 * 2);
  float* outp    = (float*)d_out;

  (void)hipMemsetAsync(counts, 0, (size_t)(N + 1) * 4, stream);
  (void)hipMemsetAsync(errs, 0, 512 * 4, stream);
  (void)hipMemsetAsync(barc, 0, 256 * 4, stream);
  (void)hipMemsetAsync(flags, 0, 256 * 4, stream);

  proj_kernel<<<128, 64, 0, stream>>>(W, Wp16);
  wpa_kernel<<<8, 256, 0, stream>>>(Wp16, WpA);
  transpose128<<<64, 256, 0, stream>>>(Om, OmT);
  int ebl = (E + 255) / 256;
  int nbl = (N + 255) / 256;  // <=256 (scanB capacity)
  hist_kernel<<<ebl, 256, 0, stream>>>(ecol, counts, E);
  scanA<<<nbl, 256, 0, stream>>>(counts, offs, bsums, N);
  scanB<<<1, 256, 0, stream>>>(bsums, nbl);
  scanC<<<nbl, 256, 0, stream>>>(offs, bsums, cursors, N, E);
  scatter_kernel<<<ebl, 256, 0, stream>>>(erow, ecol, evalp, cursors, cpair, E);

  // cooperative launch (for the co-residency guarantee); grid = R1's best
  // config: 1024 blocks (multiple of 8 for the two-level barrier)
  int dev = 0;
  (void)hipGetDevice(&dev);
  int cus = 0;
  if (hipDeviceGetAttribute(&cus, hipDeviceAttributeMultiprocessorCount, dev) != hipSuccess ||
      cus <= 0)
    cus = 256;
  int maxb = 0;
  if (hipOccupancyMaxActiveBlocksPerMultiprocessor(&maxb, (const void*)solve_kernel, 512, 0) !=
          hipSuccess ||
      maxb < 1)
    maxb = 1;
  long grid = (long)maxb * (long)cus;
  if (grid > 1024) grid = 1024;
  grid &= ~7L;
  if (grid < 8) grid = 8;

  void* args[] = {(void*)&U,    (void*)&OmT,  (void*)&WpA, (void*)&offs,
                  (void*)&cpair, (void*)&Ya,  (void*)&Yb,
                  (void*)&Bh,   (void*)&Xh,   (void*)&outp, (void*)&errs,
                  (void*)&barc, (void*)&N};
  hipError_t ce = hipLaunchCooperativeKernel((void*)solve_kernel, dim3((unsigned)grid),
                                             dim3(512), args, 0, stream);
  if (ce != hipSuccess) {
    // fallback: R4 multi-kernel path (kernel boundary = HW barrier)
    int g32 = (N + 31) / 32;
    u_gemm_kernel<<<1024, 512, 0, stream>>>(U, OmT, Ya, N);
    step_kernel<<<g32, 512, 0, stream>>>(Ya, Yb, WpA, offs, cpair, Bh, Xh, N,
                                         errs, flags, 0, 0);  // seed -> Yb
    u16* cur = Yb; u16* nxt = Ya;
    for (int t = 1; t <= T_MAX; ++t) {
      step_kernel<<<g32, 512, 0, stream>>>(cur, nxt, WpA, offs, cpair, Bh, Xh,
                                           N, errs, flags, t, 1);
      u16* tmp = cur; cur = nxt; nxt = tmp;
    }
    final_kernel<<<g32, 512, 0, stream>>>(Xh, outp, N);
  }
}

// Round 9
// 723.969 us; speedup vs baseline: 1.1271x; 1.1271x over previous
//
#include <hip/hip_runtime.h>
#include <hip/hip_fp16.h>
#include <hip/hip_cooperative_groups.h>

#define KAPPA 0.99f
#define T_MAX 32

typedef unsigned short u16;
typedef _Float16 f16x8 __attribute__((ext_vector_type(8)));
typedef float f32x4 __attribute__((ext_vector_type(4)));

static __device__ __forceinline__ f16x8 bc16(uint4 u) {
  union { uint4 a; f16x8 b; } x;
  x.a = u;
  return x.b;
}

// ---------- Projection of each row of W onto the L1 ball of radius KAPPA ----------
__global__ __launch_bounds__(64) void proj_kernel(const float* __restrict__ W,
                                                  u16* __restrict__ Wp16) {
  __shared__ float a[128];
  __shared__ float css[128];
  __shared__ float s_alpha, s_l1;
  int row = blockIdx.x;
  int t = threadIdx.x;
  a[t]      = fabsf(W[row * 128 + t]);
  a[t + 64] = fabsf(W[row * 128 + t + 64]);
  __syncthreads();
  for (int k = 2; k <= 128; k <<= 1) {
    for (int j = k >> 1; j > 0; j >>= 1) {
      int i = 2 * t - (t & (j - 1));
      int ixj = i ^ j;
      bool up = ((i & k) == 0);
      float x = a[i], y = a[ixj];
      if ((x > y) == up) { a[i] = y; a[ixj] = x; }
      __syncthreads();
    }
  }
  if (t == 0) {
    float csum = 0.f;
    int cnt = 0;
    for (int j = 0; j < 128; ++j) {
      float ad = a[127 - j];
      csum += ad;
      float c = csum - KAPPA;
      css[j] = c;
      if (ad * (float)(j + 1) > c) cnt++;
    }
    s_alpha = css[cnt - 1] / (float)cnt;
    s_l1 = csum;
  }
  __syncthreads();
  float alpha = s_alpha;
  bool doproj = (s_l1 > KAPPA);
  for (int idx = t; idx < 128; idx += 64) {
    float w = W[row * 128 + idx];
    float pp = fmaxf(fabsf(w) - alpha, 0.f);
    float res = doproj ? ((w >= 0.f) ? pp : -pp) : w;
    Wp16[row * 128 + idx] = __half_as_ushort(__float2half_rn(res));
  }
}

// repack Wp16 into MFMA A-fragment order (frag = mt*4+kt)
__global__ __launch_bounds__(256) void wpa_kernel(const u16* __restrict__ Wp16,
                                                  u16* __restrict__ WpA) {
  int idx = blockIdx.x * 256 + threadIdx.x;  // < 2048
  int l = idx & 63, frag = idx >> 6;
  int mt = frag >> 2, kt = frag & 3;
  int m = mt * 16 + (l & 15);
  int k0 = kt * 32 + (l >> 4) * 8;
  u16* dst = WpA + (size_t)idx * 8;
#pragma unroll
  for (int i = 0; i < 8; ++i) dst[i] = Wp16[m * 128 + k0 + i];
}

// ---------- 128x128 transpose (Omega -> OmegaT, fp32) ----------
__global__ __launch_bounds__(256) void transpose128(const float* __restrict__ A,
                                                    float* __restrict__ AT) {
  int idx = blockIdx.x * 256 + threadIdx.x;
  int f = idx >> 7, p = idx & 127;
  AT[p * 128 + f] = A[idx];
}

// ---------- CSR build ----------
// 8-way split histogram: R1 measured hist at 36.5us = 45ns/atomic -- cache-line
// contention (16 edges/node x 16 nodes/line = 256 atomics/line at the coherent
// point). 8 sub-histograms (by blockIdx&7) cut line contention 8x.
__global__ __launch_bounds__(256) void hist_kernel(const int* __restrict__ col,
                                                   int* __restrict__ counts8,
                                                   int N, int E) {
  int e = blockIdx.x * 256 + threadIdx.x;
  if (e < E) atomicAdd(&counts8[(blockIdx.x & 7) * (N + 1) + col[e]], 1);
}

__global__ __launch_bounds__(256) void scanA(const int* __restrict__ counts8,
                                             int* __restrict__ offs,
                                             int* __restrict__ bsums, int N) {
  __shared__ int tmp[256];
  int t = threadIdx.x, i = blockIdx.x * 256 + t;
  int v = 0;
  if (i < N) {
#pragma unroll
    for (int g = 0; g < 8; ++g) v += counts8[g * (N + 1) + i];
  }
  tmp[t] = v;
  __syncthreads();
  for (int d = 1; d < 256; d <<= 1) {
    int u = (t >= d) ? tmp[t - d] : 0;
    __syncthreads();
    tmp[t] += u;
    __syncthreads();
  }
  if (i < N) offs[i] = tmp[t] - v;
  if (t == 255) bsums[blockIdx.x] = tmp[255];
}

__global__ __launch_bounds__(256) void scanB(int* __restrict__ bsums, int nb) {
  __shared__ int tmp[256];
  int t = threadIdx.x;
  int v = (t < nb) ? bsums[t] : 0;
  tmp[t] = v;
  __syncthreads();
  for (int d = 1; d < 256; d <<= 1) {
    int u = (t >= d) ? tmp[t - d] : 0;
    __syncthreads();
    tmp[t] += u;
    __syncthreads();
  }
  if (t < nb) bsums[t] = tmp[t] - v;
}

__global__ __launch_bounds__(256) void scanC(int* __restrict__ offs,
                                             const int* __restrict__ bsums,
                                             int* __restrict__ cursors, int N, int E) {
  int i = blockIdx.x * 256 + threadIdx.x;
  if (i < N) {
    int o = offs[i] + bsums[blockIdx.x];
    offs[i] = o;
    cursors[i] = o;
  }
  if (i == 0) offs[N] = E;
}

// packed (row, val) per edge
__global__ __launch_bounds__(256) void scatter_kernel(const int* __restrict__ erow,
                                                      const int* __restrict__ ecol,
                                                      const float* __restrict__ eval,
                                                      int* __restrict__ cursors,
                                                      int2* __restrict__ cpair, int E) {
  int e = blockIdx.x * 256 + threadIdx.x;
  if (e < E) {
    int c = ecol[e];
    int pos = atomicAdd(&cursors[c], 1);
    cpair[pos] = make_int2(erow[e], __float_as_int(eval[e]));
  }
}

// ================= device helpers =================

__device__ __forceinline__ void store_half16(u16* dst, const float* acc) {
  union { u16 us[16]; uint4 q[2]; } pk;
#pragma unroll
  for (int k = 0; k < 16; ++k) pk.us[k] = __half_as_ushort(__float2half_rn(acc[k]));
  uint4* d4 = (uint4*)dst;
  d4[0] = pk.q[0];
  d4[1] = pk.q[1];
}

// Phase A: Yh = fp16(Omega @ U), feature-major U read
__device__ __forceinline__ void u_gemm_phase(const float* __restrict__ U,
                                             const float* __restrict__ OmT,
                                             u16* __restrict__ Yh, int N, int ntiles,
                                             int bid, int nblocks, int tid) {
  int n = tid & 63;
  int fg = __builtin_amdgcn_readfirstlane(tid >> 6);
  for (int tile = bid; tile < ntiles; tile += nblocks) {
    int node = tile * 64 + n;
    int nc = min(node, N - 1);
    float acc[16];
#pragma unroll
    for (int k = 0; k < 16; ++k) acc[k] = 0.f;
    for (int j = 0; j < 128; ++j) {
      float x = U[(size_t)j * N + nc];
      const float* wr = OmT + j * 128 + fg * 16;
#pragma unroll
      for (int k = 0; k < 16; ++k) acc[k] = fmaf(wr[k], x, acc[k]);
    }
    if (node < N) store_half16(Yh + (size_t)node * 128 + fg * 16, acc);
  }
}

// 8-way-split error slots: max over groups
__device__ __forceinline__ float err_at(const unsigned* __restrict__ errs, int t) {
  unsigned m = 0u;
#pragma unroll
  for (int g = 0; g < 8; ++g) {
    unsigned v = __hip_atomic_load(errs + t * 8 + g, __ATOMIC_RELAXED,
                                   __HIP_MEMORY_SCOPE_AGENT);
    m = (v > m) ? v : m;
  }
  return __uint_as_float(m);
}

// stop rule, robust to the fp16 quantization floor (unchanged from the passing
// R1/R4/R7/R8 runs -- all landed absmax at the fp16 floor 2^-9)
__device__ __forceinline__ bool stop_rule(float e, float prev) {
  return (e < 2e-3f) || (e < 4e-3f && e < 0.6f * prev) ||
         (e < 3e-3f && e > 0.9f * prev);
}

__device__ __forceinline__ void load_afrags(const u16* __restrict__ WpA, int wave,
                                            int lane, f16x8* afrag) {
  const uint4* ag = (const uint4*)WpA;
#pragma unroll
  for (int kt = 0; kt < 4; ++kt) afrag[kt] = bc16(ag[(wave * 4 + kt) * 64 + lane]);
}

// Fused pass over statically partitioned 32-node tiles. Double-buffered
// synchronous Jacobi (R1's proven-fastest structure; R6 showed async/in-place
// is slower per sweep AND needs more sweeps).
// Lockstep gather: the wave's 4 rows advance together in 8-deep chunks
// (32 Y-gathers in flight). Rows clamped to N-1: duplicate writes benign.
// mode 0 (seed): B=gather(Y); Bh=Xh=fp16(B); Ydst=fp16(Wp@B)
// mode 1 (step): x=relu(gather(Y)+B); err vs Xh; Xh=fp16(x); Ydst=fp16(Wp@x)
__device__ __forceinline__ void fused_tile_pass(
    const u16* __restrict__ Ysrc, u16* __restrict__ Ydst,
    const int* __restrict__ offs, const int2* __restrict__ cpair,
    u16* __restrict__ Bh, u16* __restrict__ Xh, int N, int mode,
    unsigned* err_slot, const f16x8* afrag, __half2 (*xs)[72],
    float* werr, int bid, int nblocks, int tid, int lane, int wave) {
  const __half2* Y2 = (const __half2*)Ysrc;
  __half2* B2 = (__half2*)Bh;
  __half2* X2 = (__half2*)Xh;
  int ntiles = (N + 31) >> 5;
  float m = 0.f;
  for (int tile = bid; tile < ntiles; tile += nblocks) {
    __syncthreads();  // prev tile's MFMA reads of xs done
    int base = tile * 32;
    int cq[4], end[4], last[4], e[4];
    float ax[4], ay[4];
#pragma unroll
    for (int q = 0; q < 4; ++q) {
      int c = base + wave * 4 + q;
      cq[q] = min(c, N - 1);
      int b = offs[cq[q]];
      end[q] = offs[cq[q] + 1];
      last[q] = (end[q] > b) ? (end[q] - 1) : 0;
      e[q] = b;
      ax[q] = 0.f;
      ay[q] = 0.f;
    }
    for (;;) {
      int more = 0;
#pragma unroll
      for (int q = 0; q < 4; ++q) more |= (e[q] < end[q]) ? 1 : 0;
      if (!more) break;
      int addr[4][8];
      float val[4][8];
#pragma unroll
      for (int q = 0; q < 4; ++q) {
#pragma unroll
        for (int i = 0; i < 8; ++i) {
          int idx = e[q] + i;
          int cl = (idx <= last[q]) ? idx : last[q];
          int2 pp = cpair[cl];
          addr[q][i] = pp.x * 64 + lane;
          val[q][i] = (idx < end[q]) ? __int_as_float(pp.y) : 0.f;
        }
      }
      __half2 h[4][8];
#pragma unroll
      for (int q = 0; q < 4; ++q)
#pragma unroll
        for (int i = 0; i < 8; ++i) h[q][i] = Y2[addr[q][i]];
#pragma unroll
      for (int q = 0; q < 4; ++q)
#pragma unroll
        for (int i = 0; i < 8; ++i) {
          ax[q] = fmaf(val[q][i], __low2float(h[q][i]), ax[q]);
          ay[q] = fmaf(val[q][i], __high2float(h[q][i]), ay[q]);
        }
#pragma unroll
      for (int q = 0; q < 4; ++q) e[q] += 8;
    }
#pragma unroll
    for (int q = 0; q < 4; ++q) {
      int nl = wave * 4 + q;
      size_t wi = (size_t)cq[q] * 64 + lane;
      float axv = ax[q], ayv = ay[q];
      if (mode == 0) {
        __half2 hh = __floats2half2_rn(axv, ayv);
        B2[wi] = hh;
        X2[wi] = hh;
        xs[nl][lane] = hh;
      } else {
        __half2 b = B2[wi];
        axv = fmaxf(axv + __low2float(b), 0.f);
        ayv = fmaxf(ayv + __high2float(b), 0.f);
        __half2 xo = X2[wi];
        m = fmaxf(m, fmaxf(fabsf(axv - __low2float(xo)),
                           fabsf(ayv - __high2float(xo))));
        __half2 hh = __floats2half2_rn(axv, ayv);
        X2[wi] = hh;
        xs[nl][lane] = hh;
      }
    }
    __syncthreads();
    // MFMA: wave w computes M-tile w of Wp @ X(128x32)
    f32x4 acc0 = {0.f, 0.f, 0.f, 0.f};
    f32x4 acc1 = {0.f, 0.f, 0.f, 0.f};
    int nA = lane & 15;
    int q4 = (lane >> 4) * 4;
#pragma unroll
    for (int kt = 0; kt < 4; ++kt) {
      int h0 = kt * 16 + q4;
      f16x8 b0 = bc16(*(const uint4*)&xs[nA][h0]);
      f16x8 b1 = bc16(*(const uint4*)&xs[16 + nA][h0]);
      acc0 = __builtin_amdgcn_mfma_f32_16x16x32_f16(afrag[kt], b0, acc0, 0, 0, 0);
      acc1 = __builtin_amdgcn_mfma_f32_16x16x32_f16(afrag[kt], b1, acc1, 0, 0, 0);
    }
    // D layout: col=lane&15 (node), row=(lane>>4)*4+reg (feat in M-tile)
    int fb = wave * 16 + q4;
    int n0 = base + nA;
    if (n0 < N) {
      __half2* d = (__half2*)(Ydst + (size_t)n0 * 128 + fb);
      d[0] = __floats2half2_rn(acc0.x, acc0.y);
      d[1] = __floats2half2_rn(acc0.z, acc0.w);
    }
    int n1 = base + 16 + nA;
    if (n1 < N) {
      __half2* d = (__half2*)(Ydst + (size_t)n1 * 128 + fb);
      d[0] = __floats2half2_rn(acc1.x, acc1.y);
      d[1] = __floats2half2_rn(acc1.z, acc1.w);
    }
  }
  if (mode == 1) {
#pragma unroll
    for (int o = 32; o > 0; o >>= 1) m = fmaxf(m, __shfl_xor(m, o, 64));
    if (lane == 0) werr[wave] = m;
    __syncthreads();
    if (tid == 0) {
      float bm = werr[0];
#pragma unroll
      for (int w = 1; w < 8; ++w) bm = fmaxf(bm, werr[w]);
      atomicMax(err_slot + (bid & 7), __float_as_uint(bm));  // 8-way split
    }
  }
}

// Output pass: out[f][node] = float(Xh[node][f]), transposed via LDS.
// Tile partition matches fused_tile_pass: block reads only rows it wrote.
__device__ __forceinline__ void xh_transpose_pass(const u16* __restrict__ Xh,
                                                  float* __restrict__ out, int N,
                                                  float (*Ts)[129], int bid,
                                                  int nblocks, int tid) {
  const uint4* X4 = (const uint4*)Xh;  // 16 uint4 per 128-feat row
  int ntiles = (N + 31) >> 5;
  for (int tile = bid; tile < ntiles; tile += nblocks) {
    __syncthreads();
    int base = tile * 32;
    {
      int nn = tid >> 4, cc = tid & 15;  // 512 threads = 32 rows x 16 uint4
      uint4 q = make_uint4(0, 0, 0, 0);
      if (base + nn < N) q = X4[(size_t)(base + nn) * 16 + cc];
      f16x8 h = bc16(q);
      float* dst = &Ts[nn][cc * 8];
#pragma unroll
      for (int j = 0; j < 8; ++j) dst[j] = (float)h[j];
    }
    __syncthreads();
    int n = tid & 31, f0 = tid >> 5;
    int node = base + n;
    if (node < N) {
#pragma unroll
      for (int k = 0; k < 8; ++k) {
        int f = f0 + k * 16;
        out[(size_t)f * N + node] = Ts[n][f];
      }
    }
  }
}

// ================= cooperative solver (R1 structure: cg.sync per sweep) =======
// Barrier ledger (measured): cg.sync ~28us; custom two-level relaxed/acq
// variants 40-57us or livelock; kernel-boundary = L2 cold (+170us/pass).
// cg.sync is the floor on this chip; sweeps (~10us) sit at the cross-XCD
// L3-traffic roofline (~190 MB/sweep).
__global__ __launch_bounds__(512, 4) void solve_kernel(
    const float* __restrict__ U, const float* __restrict__ OmT,
    const u16* __restrict__ WpA, const int* __restrict__ offs,
    const int2* __restrict__ cpair, u16* __restrict__ Ya, u16* __restrict__ Yb,
    u16* __restrict__ Bh, u16* __restrict__ Xh, float* __restrict__ out,
    unsigned* __restrict__ errs, int N) {
  cooperative_groups::grid_group grid = cooperative_groups::this_grid();
  __shared__ __align__(16) char lds_raw[32 * 129 * 4];  // Ts(16512) >= xs(9216)
  __shared__ float werr[8];
  __shared__ float s_e;
  __half2 (*xs)[72] = (__half2(*)[72])lds_raw;
  float (*Ts)[129] = (float(*)[129])lds_raw;
  const int tid = threadIdx.x;
  const int bid = blockIdx.x, nblocks = gridDim.x;
  const int lane = tid & 63, wave = tid >> 6;
  const int ntiles64 = (N + 63) >> 6;

  f16x8 afrag[4];
  load_afrags(WpA, wave, lane, afrag);

  u_gemm_phase(U, OmT, Ya, N, ntiles64, bid, nblocks, tid);
  grid.sync();
  // seed: B = gather(Om@U from Ya); X0 = B; Yb = Wp@B
  fused_tile_pass(Ya, Yb, offs, cpair, Bh, Xh, N, 0, nullptr, afrag, xs, werr,
                  bid, nblocks, tid, lane, wave);
  grid.sync();

  u16* cur = Yb;
  u16* nxt = Ya;
  float prev = 3.0e38f;
  for (int t = 1; t <= T_MAX; ++t) {
    fused_tile_pass(cur, nxt, offs, cpair, Bh, Xh, N, 1, errs + t * 8, afrag, xs,
                    werr, bid, nblocks, tid, lane, wave);
    grid.sync();
    if (tid == 0) s_e = err_at(errs, t);
    __syncthreads();
    float e = s_e;
    u16* tmp = cur; cur = nxt; nxt = tmp;
    if (stop_rule(e, prev)) break;  // grid-uniform: same slots read by all blocks
    prev = e;
  }

  // output X_T directly (block reads only tiles it wrote: no barrier needed)
  xh_transpose_pass(Xh, out, N, Ts, bid, nblocks, tid);
}

// ================= fallback multi-kernel path (R4, known-good) =================
__global__ __launch_bounds__(512) void u_gemm_kernel(const float* __restrict__ U,
                                                     const float* __restrict__ OmT,
                                                     u16* __restrict__ Yh, int N) {
  u_gemm_phase(U, OmT, Yh, N, (N + 63) >> 6, blockIdx.x, gridDim.x, threadIdx.x);
}

__device__ __forceinline__ bool stop_before_fb(const unsigned* errs, int upto) {
  float prev = 3.0e38f;
  for (int s = 1; s <= upto; ++s) {
    float e = err_at(errs, s);
    if (stop_rule(e, prev)) return true;
    prev = e;
  }
  return false;
}

__global__ __launch_bounds__(512, 4) void step_kernel(
    const u16* __restrict__ Ysrc, u16* __restrict__ Ydst,
    const u16* __restrict__ WpA, const int* __restrict__ offs,
    const int2* __restrict__ cpair, u16* __restrict__ Bh, u16* __restrict__ Xh,
    int N, unsigned* __restrict__ errs, int* __restrict__ flags, int t, int mode) {
  if (mode == 1 && t > 1) {
    int sf = __hip_atomic_load(&flags[64], __ATOMIC_RELAXED,
                               __HIP_MEMORY_SCOPE_AGENT);
    if (sf != 0 && t > sf) return;
  }
  __shared__ __align__(16) __half2 xs[32][72];
  __shared__ float werr[8];
  int lane = threadIdx.x & 63, wave = threadIdx.x >> 6;
  f16x8 afrag[4];
  load_afrags(WpA, wave, lane, afrag);
  // one tile per block: bid indexes the tile, nblocks = ntiles
  fused_tile_pass(Ysrc, Ydst, offs, cpair, Bh, Xh, N, mode,
                  (mode == 1) ? (errs + t * 8) : nullptr, afrag, xs, werr,
                  blockIdx.x, gridDim.x, threadIdx.x, lane, wave);
  if (mode == 1 && threadIdx.x == 0) {
    __threadfence();
    int old = __hip_atomic_fetch_add(&flags[t], 1, __ATOMIC_ACQ_REL,
                                     __HIP_MEMORY_SCOPE_AGENT);
    if (old == (int)gridDim.x - 1) {
      float e = err_at(errs, t);
      float prev = (t > 1) ? err_at(errs, t - 1) : 3.0e38f;
      int fired = stop_rule(e, prev) ? t : 0;
      if (t == 1)
        __hip_atomic_store(&flags[64], fired, __ATOMIC_RELEASE,
                           __HIP_MEMORY_SCOPE_AGENT);
      else if (fired && __hip_atomic_load(&flags[64], __ATOMIC_RELAXED,
                                          __HIP_MEMORY_SCOPE_AGENT) == 0)
        __hip_atomic_store(&flags[64], fired, __ATOMIC_RELEASE,
                           __HIP_MEMORY_SCOPE_AGENT);
    }
  }
}

__global__ __launch_bounds__(512) void final_kernel(const u16* __restrict__ Xh,
                                                    float* __restrict__ out, int N) {
  __shared__ float Ts[32][129];
  xh_transpose_pass(Xh, out, N, Ts, blockIdx.x, gridDim.x, threadIdx.x);
}

extern "C" void kernel_launch(void* const* d_in, const int* in_sizes, int n_in,
                              void* d_out, int out_size, void* d_ws, size_t ws_size,
                              hipStream_t stream) {
  const float* W     = (const float*)d_in[0];
  const float* Om    = (const float*)d_in[1];
  const float* U     = (const float*)d_in[2];
  const float* evalp = (const float*)d_in[3];
  const int*   erow  = (const int*)d_in[4];
  const int*   ecol  = (const int*)d_in[5];

  int N = in_sizes[2] / 128;
  int E = in_sizes[3];

  char* p = (char*)d_ws;
  auto alloc = [&](size_t bytes) {
    char* r = p;
    p += (bytes + 255) & ~(size_t)255;
    return r;
  };
  u16* Wp16      = (u16*)alloc(128 * 128 * 2);
  u16* WpA       = (u16*)alloc(32 * 64 * 8 * 2);  // MFMA A-fragment layout
  float* OmT     = (float*)alloc(128 * 128 * 4);
  int* counts8   = (int*)alloc((size_t)8 * (N + 1) * 4);  // split histogram
  int* offs      = (int*)alloc((size_t)(N + 1) * 4);
  int* cursors   = (int*)alloc((size_t)N * 4);
  int* bsums     = (int*)alloc(1024 * 4);
  unsigned* errs = (unsigned*)alloc(512 * 4);   // [t*8+group] split err slots
  int* flags     = (int*)alloc(256 * 4);        // fallback arrive/stop state
  int2* cpair    = (int2*)alloc((size_t)E * 8); // packed (row, val_bits)
  u16* Ya        = (u16*)alloc((size_t)N * 128 * 2);
  u16* Yb        = (u16*)alloc((size_t)N * 128 * 2);
  u16* Bh        = (u16*)alloc((size_t)N * 128 * 2);
  u16* Xh        = (u16*)alloc((size_t)N * 128 * 2);
  float* outp    = (float*)d_out;

  (void)hipMemsetAsync(counts8, 0, (size_t)8 * (N + 1) * 4, stream);
  (void)hipMemsetAsync(errs, 0, 512 * 4, stream);
  (void)hipMemsetAsync(flags, 0, 256 * 4, stream);

  proj_kernel<<<128, 64, 0, stream>>>(W, Wp16);
  wpa_kernel<<<8, 256, 0, stream>>>(Wp16, WpA);
  transpose128<<<64, 256, 0, stream>>>(Om, OmT);
  int ebl = (E + 255) / 256;
  int nbl = (N + 255) / 256;  // <=256 (scanB capacity)
  hist_kernel<<<ebl, 256, 0, stream>>>(ecol, counts8, N, E);
  scanA<<<nbl, 256, 0, stream>>>(counts8, offs, bsums, N);
  scanB<<<1, 256, 0, stream>>>(bsums, nbl);
  scanC<<<nbl, 256, 0, stream>>>(offs, bsums, cursors, N, E);
  scatter_kernel<<<ebl, 256, 0, stream>>>(erow, ecol, evalp, cursors, cpair, E);

  // cooperative grid sized from runtime occupancy (pure queries, capture-safe)
  int dev = 0;
  (void)hipGetDevice(&dev);
  int cus = 0;
  if (hipDeviceGetAttribute(&cus, hipDeviceAttributeMultiprocessorCount, dev) != hipSuccess ||
      cus <= 0)
    cus = 256;
  int maxb = 0;
  if (hipOccupancyMaxActiveBlocksPerMultiprocessor(&maxb, (const void*)solve_kernel, 512, 0) !=
          hipSuccess ||
      maxb < 1)
    maxb = 1;
  long grid = (long)maxb * (long)cus;
  if (grid > 1024) grid = 1024;

  void* args[] = {(void*)&U,    (void*)&OmT,  (void*)&WpA, (void*)&offs,
                  (void*)&cpair, (void*)&Ya,  (void*)&Yb,
                  (void*)&Bh,   (void*)&Xh,   (void*)&outp, (void*)&errs,
                  (void*)&N};
  hipError_t ce = hipLaunchCooperativeKernel((void*)solve_kernel, dim3((unsigned)grid),
                                             dim3(512), args, 0, stream);
  if (ce != hipSuccess) {
    // fallback: R4 multi-kernel path (kernel boundary = HW barrier)
    int g32 = (N + 31) / 32;
    u_gemm_kernel<<<1024, 512, 0, stream>>>(U, OmT, Ya, N);
    step_kernel<<<g32, 512, 0, stream>>>(Ya, Yb, WpA, offs, cpair, Bh, Xh, N,
                                         errs, flags, 0, 0);  // seed -> Yb
    u16* cur = Yb; u16* nxt = Ya;
    for (int t = 1; t <= T_MAX; ++t) {
      step_kernel<<<g32, 512, 0, stream>>>(cur, nxt, WpA, offs, cpair, Bh, Xh,
                                           N, errs, flags, t, 1);
      u16* tmp = cur; cur = nxt; nxt = tmp;
    }
    final_kernel<<<g32, 512, 0, stream>>>(Xh, outp, N);
  }
}